// Round 18
// baseline (116.186 us; speedup 1.0000x reference)
//
#include <hip/hip_runtime.h>
#include <cstddef>

#define EMBED 1024
#define HEADS 16
#define HDIM  64
#define BATCH 2
#define SEQ   2048
#define MTOT  (BATCH*SEQ)

typedef __attribute__((ext_vector_type(8)))  short short8;   // 8 bf16 = 4 VGPRs
typedef __attribute__((ext_vector_type(4)))  float f32x4;    // 16x16 C/D frag
typedef __attribute__((ext_vector_type(16))) float f32x16;   // 32x32 C/D frag

typedef __attribute__((address_space(1))) const unsigned int* gas_u32p;
typedef __attribute__((address_space(3))) unsigned int* las_u32p;

// async global->LDS, 16B per lane; LDS dest = wave-uniform base + lane*16
static __device__ __forceinline__ void gload_lds16(const void* g, void* l) {
    __builtin_amdgcn_global_load_lds((gas_u32p)g, (las_u32p)l, 16, 0, 0);
}

// fp32 -> bf16 round-to-nearest-even
static __device__ __forceinline__ unsigned short f2bf(float x) {
    unsigned u = __builtin_bit_cast(unsigned, x);
    unsigned r = (u + 0x7FFFu + ((u >> 16) & 1u)) >> 16;
    return (unsigned short)r;
}

// pack two fp32 -> one u32 of 2 bf16 (hardware cvt)
static __device__ __forceinline__ unsigned pk_bf16(float lo, float hi) {
    unsigned r;
    asm("v_cvt_pk_bf16_f32 %0, %1, %2" : "=v"(r) : "v"(lo), "v"(hi));
    return r;
}

// swap: a' = {a.lo-lanes | b.lo-lanes}, b' = {a.hi-lanes | b.hi-lanes}
static __device__ __forceinline__ void plane32_swap(unsigned &a, unsigned &b) {
    auto r = __builtin_amdgcn_permlane32_swap((int)a, (int)b, false, false);
    a = (unsigned)r[0];
    b = (unsigned)r[1];
}

static __device__ __forceinline__ f32x16 mfma32(short8 a, short8 b, f32x16 c) {
    return __builtin_amdgcn_mfma_f32_32x32x16_bf16(a, b, c, 0, 0, 0);
}

// ---------------------------------------------------------------------------
// conv_all: x (4M elems) then Wq|Wk|Wv|Wo (4x1M elems) fp32 -> bf16 (unchanged)
// ---------------------------------------------------------------------------
__global__ __launch_bounds__(256)
void conv_all(const float* __restrict__ x,
              const float* __restrict__ Wq, const float* __restrict__ Wk,
              const float* __restrict__ Wv, const float* __restrict__ Wo,
              unsigned short* __restrict__ xh, unsigned short* __restrict__ Wh)
{
    const size_t i = ((size_t)blockIdx.x * 256 + threadIdx.x) * 8;
    const size_t XTOT = (size_t)MTOT * EMBED;           // 4M
    const float* src;
    unsigned short* dst;
    size_t off;
    if (i < XTOT) {
        src = x; dst = xh; off = i;
    } else {
        size_t j = i - XTOT;
        int sel = (int)(j >> 20);
        off = j & ((1u << 20) - 1);
        src = sel == 0 ? Wq : sel == 1 ? Wk : sel == 2 ? Wv : Wo;
        dst = Wh + ((size_t)sel << 20);
    }
    float4 a = *(const float4*)(src + off);
    float4 b = *(const float4*)(src + off + 4);
    unsigned short o[8] __attribute__((aligned(16)));
    o[0] = f2bf(a.x); o[1] = f2bf(a.y); o[2] = f2bf(a.z); o[3] = f2bf(a.w);
    o[4] = f2bf(b.x); o[5] = f2bf(b.y); o[6] = f2bf(b.z); o[7] = f2bf(b.w);
    *(uint4*)(dst + off) = *(const uint4*)o;
}

// ---------------------------------------------------------------------------
// Fused QKV GEMM v3 (R17-proven): 256x256 tile, BK=32, 3-buffer rotation,
// counted vmcnt(4). UNCHANGED.
// ---------------------------------------------------------------------------
__global__ __launch_bounds__(512, 2)
void gemm_qkv_pipe(const unsigned short* __restrict__ A,
                   const unsigned short* __restrict__ Wqh,
                   const unsigned short* __restrict__ Wkh,
                   const unsigned short* __restrict__ Wvh,
                   const float* __restrict__ bq,
                   const float* __restrict__ bk,
                   const float* __restrict__ bv,
                   unsigned short* __restrict__ Qb,
                   unsigned short* __restrict__ Kb,
                   unsigned short* __restrict__ Vt)
{
    __shared__ short AL[3][256 * 32];   // 3 x 16KB
    __shared__ short BL[3][256 * 32];   // 3 x 16KB   (96KB total)

    const int tid  = threadIdx.x;
    const int lane = tid & 63;
    const int w    = tid >> 6;        // 0..7
    const int wm   = w >> 2;          // 0..1 : A-half (rows wm*128..+127)
    const int wn   = w & 3;           // 0..3 : B-quarter (cols wn*64..+63)
    const int c    = lane & 15;
    const int g    = lane >> 4;

    const int m0   = blockIdx.y * 256;
    const int wsel = blockIdx.x >> 2;
    const int n0   = (blockIdx.x & 3) * 256;

    const unsigned short* W = (wsel == 0) ? Wqh : (wsel == 1) ? Wkh : Wvh;
    const float* bias       = (wsel == 0) ? bq  : (wsel == 1) ? bk  : bv;

    const int r0 = tid >> 2;                       // 0..127
    const int sc = (tid & 3) ^ ((r0 >> 1) & 3);
    const unsigned short* aS0 = A + (size_t)(m0 + r0)       * EMBED + sc * 8;
    const unsigned short* aS1 = A + (size_t)(m0 + 128 + r0) * EMBED + sc * 8;
    const unsigned short* bS0 = W + (size_t)(n0 + r0)       * EMBED + sc * 8;
    const unsigned short* bS1 = W + (size_t)(n0 + 128 + r0) * EMBED + sc * 8;
    const int d0 = w * 512;
    const int d1 = 4096 + w * 512;

    #define STG_A(bj) do {                         \
        gload_lds16(aS0, &AL[bj][d0]);             \
        gload_lds16(aS1, &AL[bj][d1]);             \
        aS0 += 32; aS1 += 32; } while (0)
    #define STG_B(bj) do {                         \
        gload_lds16(bS0, &BL[bj][d0]);             \
        gload_lds16(bS1, &BL[bj][d1]);             \
        bS0 += 32; bS1 += 32; } while (0)

    f32x4 acc[8][4] = {};

    STG_A(0); STG_B(0);
    STG_A(1); STG_B(1);
    asm volatile("s_waitcnt vmcnt(4)" ::: "memory");
    __builtin_amdgcn_s_barrier();

    for (int j = 0; j < 32; ++j) {
        const int cb = j % 3;
        const int nb = (j + 2) % 3;
        const short* Ab = &AL[cb][0];
        const short* Bb = &BL[cb][0];

        short8 af[4], bf[4];

        #pragma unroll
        for (int ni = 0; ni < 4; ++ni) {
            const int row = wn * 64 + ni * 16 + c;
            const int cn  = g ^ ((row >> 1) & 3);
            bf[ni] = *(const short8*)&Bb[row * 32 + cn * 8];
        }
        #pragma unroll
        for (int mi = 0; mi < 4; ++mi) {
            const int row = wm * 128 + mi * 16 + c;
            const int cn  = g ^ ((row >> 1) & 3);
            af[mi] = *(const short8*)&Ab[row * 32 + cn * 8];
        }
        if (j < 30) STG_A(nb);
        __builtin_amdgcn_s_barrier();
        __builtin_amdgcn_s_setprio(1);
        #pragma unroll
        for (int mi = 0; mi < 4; ++mi)
            #pragma unroll
            for (int ni = 0; ni < 4; ++ni)
                acc[mi][ni] = __builtin_amdgcn_mfma_f32_16x16x32_bf16(
                    af[mi], bf[ni], acc[mi][ni], 0, 0, 0);
        __builtin_amdgcn_s_setprio(0);
        __builtin_amdgcn_s_barrier();

        #pragma unroll
        for (int mi = 0; mi < 4; ++mi) {
            const int row = wm * 128 + 64 + mi * 16 + c;
            const int cn  = g ^ ((row >> 1) & 3);
            af[mi] = *(const short8*)&Ab[row * 32 + cn * 8];
        }
        if (j < 30) STG_B(nb);
        __builtin_amdgcn_s_barrier();
        __builtin_amdgcn_s_setprio(1);
        #pragma unroll
        for (int mi = 0; mi < 4; ++mi)
            #pragma unroll
            for (int ni = 0; ni < 4; ++ni)
                acc[4 + mi][ni] = __builtin_amdgcn_mfma_f32_16x16x32_bf16(
                    af[mi], bf[ni], acc[4 + mi][ni], 0, 0, 0);
        __builtin_amdgcn_s_setprio(0);
        if (j < 30)       asm volatile("s_waitcnt vmcnt(4)" ::: "memory");
        else if (j == 30) asm volatile("s_waitcnt vmcnt(0)" ::: "memory");
        __builtin_amdgcn_s_barrier();
    }
    #undef STG_A
    #undef STG_B

    if (wsel == 2) {
        #pragma unroll
        for (int mi8 = 0; mi8 < 8; ++mi8) {
            const int m  = m0 + wm * 128 + (mi8 >> 2) * 64 + (mi8 & 3) * 16 + g * 4;
            const int bb = m >> 11;
            const int ss = m & (SEQ - 1);
            #pragma unroll
            for (int ni = 0; ni < 4; ++ni) {
                const int col = n0 + wn * 64 + ni * 16 + c;
                const int hh = col >> 6, dd = col & 63;
                const float bi_ = bias[col];
                ushort4 o;
                o.x = f2bf(acc[mi8][ni][0] + bi_);
                o.y = f2bf(acc[mi8][ni][1] + bi_);
                o.z = f2bf(acc[mi8][ni][2] + bi_);
                o.w = f2bf(acc[mi8][ni][3] + bi_);
                *(ushort4*)&Vt[((size_t)((bb * HEADS + hh) * HDIM) + dd) * SEQ + ss] = o;
            }
        }
    } else {
        unsigned short* Out = (wsel == 0) ? Qb : Kb;
        const float oscale  = (wsel == 0) ? 0.180336880f : 1.0f;  // 0.125*log2(e)
        #pragma unroll
        for (int mi8 = 0; mi8 < 8; ++mi8)
            #pragma unroll
            for (int r = 0; r < 4; ++r) {
                const int m = m0 + wm * 128 + (mi8 >> 2) * 64 + (mi8 & 3) * 16
                            + g * 4 + r;
                #pragma unroll
                for (int ni = 0; ni < 4; ++ni) {
                    const int col = n0 + wn * 64 + ni * 16 + c;
                    Out[(size_t)m * EMBED + col] =
                        f2bf((acc[mi8][ni][r] + bias[col]) * oscale);
                }
            }
    }
}

// ---------------------------------------------------------------------------
// Output GEMM: R13-proven mirror of R12 (BK=64 + source-XOR swizzle).
// UNCHANGED.
// ---------------------------------------------------------------------------
__global__ __launch_bounds__(256)
void gemm_o_bf16(const unsigned short* __restrict__ A,
                 const unsigned short* __restrict__ Woh,
                 const float* __restrict__ bo,
                 float* __restrict__ C)
{
    __shared__ short As[128 * 64];
    __shared__ short Bs[128 * 64];

    const int tid  = threadIdx.x;
    const int lane = tid & 63;
    const int w    = tid >> 6;
    const int c    = lane & 15;
    const int g    = lane >> 4;
    const int wr   = w >> 1;
    const int wc   = w & 1;

    const int m0 = blockIdx.y * 128;
    const int n0 = blockIdx.x * 128;

    f32x4 acc[4][4] = {};

    for (int k0 = 0; k0 < EMBED; k0 += 64) {
        __syncthreads();
        #pragma unroll
        for (int i = 0; i < 4; ++i) {
            const int slot = w * 256 + i * 64 + lane;
            const int row  = slot >> 3;
            const int chs  = (slot & 7) ^ (row & 7);
            gload_lds16(A   + (size_t)(m0 + row) * EMBED + k0 + chs * 8,
                        As + (size_t)(w * 256 + i * 64) * 8);
            gload_lds16(Woh + (size_t)(n0 + row) * EMBED + k0 + chs * 8,
                        Bs + (size_t)(w * 256 + i * 64) * 8);
        }
        __syncthreads();

        #pragma unroll
        for (int ks = 0; ks < 2; ++ks) {
            short8 af[4], bf[4];
            #pragma unroll
            for (int mi = 0; mi < 4; ++mi) {
                const int row = wr * 64 + mi * 16 + c;
                const int chn = (ks * 4 + g) ^ (row & 7);
                af[mi] = *(const short8*)&As[row * 64 + chn * 8];
            }
            #pragma unroll
            for (int ni = 0; ni < 4; ++ni) {
                const int row = wc * 64 + ni * 16 + c;
                const int chn = (ks * 4 + g) ^ (row & 7);
                bf[ni] = *(const short8*)&Bs[row * 64 + chn * 8];
            }
            #pragma unroll
            for (int mi = 0; mi < 4; ++mi)
                #pragma unroll
                for (int ni = 0; ni < 4; ++ni)
                    acc[mi][ni] = __builtin_amdgcn_mfma_f32_16x16x32_bf16(
                        af[mi], bf[ni], acc[mi][ni], 0, 0, 0);
        }
    }

    #pragma unroll
    for (int mi = 0; mi < 4; ++mi)
        #pragma unroll
        for (int r = 0; r < 4; ++r) {
            const int m = m0 + wr * 64 + mi * 16 + g * 4 + r;
            #pragma unroll
            for (int ni = 0; ni < 4; ++ni) {
                const int col = n0 + wc * 64 + ni * 16 + c;
                C[(size_t)m * EMBED + col] = acc[mi][ni][r] + bo[col];
            }
        }
}

// ---------------------------------------------------------------------------
// MFMA flash attention v9 = v5 math exactly, SINGLE-buffered K/V (32KB LDS
// -> 4 blocks/CU = 8 waves/SIMD at VGPR 64; R12 recipe: single-buffer +
// occupancy beats dbuf prefetch). Loop: sync -> stage -> sync(drain) ->
// compute. Merge re-sequenced in two 16KB dt-rounds so scratch (16.5KB)
// overlays the 32KB K/V region (R14 lesson: never exceed the power-of-2).
// ---------------------------------------------------------------------------
__global__ __launch_bounds__(512, 4)
void flash_attn_mfma9(const unsigned short* __restrict__ Qb,
                      const unsigned short* __restrict__ Kb,
                      const unsigned short* __restrict__ Vt,
                      unsigned short* __restrict__ O)
{
    __shared__ short SLDS[16384];         // 32KB: K[half][4096] | V at +8192

    const int tid  = threadIdx.x;
    const int lane = tid & 63;
    const int w    = tid >> 6;            // 0..7
    const int qt   = w & 3;               // q subtile
    const int half = w >> 2;              // kv half
    const int l31  = lane & 31;
    const int hi   = lane >> 5;
    const int q0   = blockIdx.x * 128 + qt * 32;
    const int h    = blockIdx.y;
    const int b    = blockIdx.z;

    // persistent Q B-frags: qf[kc] holds Q[q=l31][d = kc*16 + hi*8 + j]
    short8 qf[4];
    {
        const unsigned short* qrow =
            Qb + (size_t)(b * SEQ + q0 + l31) * EMBED + h * HDIM + hi * 8;
        #pragma unroll
        for (int kc = 0; kc < 4; ++kc)
            qf[kc] = *(const short8*)(qrow + kc * 16);
    }

    // staging: tile tb = w>>1 (0=K_lo,1=V_lo,2=K_hi,3=V_hi), ssub = w&1.
    const int tb     = w >> 1;
    const int sthalf = tb >> 1;
    const int stV    = tb & 1;
    const int ssub   = w & 1;
    const int strow  = ssub * 32 + (lane >> 3);
    const int ch     = (lane & 7) ^ (strow & 7);
    const unsigned short* kS =
        Kb + (size_t)(b * SEQ + sthalf * (SEQ / 2) + strow) * EMBED + h * HDIM + ch * 8;
    const unsigned short* vS =
        Vt + ((size_t)((b * HEADS + h) * HDIM) + strow) * SEQ + sthalf * (SEQ / 2) + ch * 8;
    short* sdst = stV ? &SLDS[8192 + sthalf * 4096 + ssub * 2048]
                      : &SLDS[sthalf * 4096 + ssub * 2048];

    const short* kb_ = &SLDS[half * 4096];
    const short* vb_ = &SLDS[8192 + half * 4096];

    f32x16 acc[2] = {};
    float l_run = 0.f;

    for (int kt = 0; kt < SEQ / 2 / 64; ++kt) {
        __syncthreads();                  // prev iter's LDS reads complete
        if (stV == 0) {
            const unsigned short* src = kS + (size_t)kt * 64 * EMBED;
            #pragma unroll
            for (int it = 0; it < 4; ++it)
                gload_lds16(src + (size_t)it * 8 * EMBED, sdst + it * 512);
        } else {
            const unsigned short* src = vS + kt * 64;
            #pragma unroll
            for (int it = 0; it < 4; ++it)
                gload_lds16(src + (size_t)it * 8 * SEQ, sdst + it * 512);
        }
        __syncthreads();                  // drains vmcnt(0): tiles ready

        // ---- QK^T (C: col=l31=q, row=kv via qr formula)
        f32x16 s[2] = {};
        __builtin_amdgcn_s_setprio(1);
        #pragma unroll
        for (int t = 0; t < 2; ++t) {
            const int row = t * 32 + l31;
            const int rm  = l31 & 7;
            #pragma unroll
            for (int kc = 0; kc < 4; ++kc) {
                short8 ka = *(const short8*)&kb_[row * 64 + (((2 * kc + hi) ^ rm) * 8)];
                s[t] = mfma32(ka, qf[kc], s[t]);
            }
        }
        __builtin_amdgcn_s_setprio(0);

        // ---- P = exp2(s'), row-sum (fixed-base softmax: no max machinery)
        float rs = 0.f;
        #pragma unroll
        for (int t = 0; t < 2; ++t)
            #pragma unroll
            for (int r = 0; r < 16; ++r) {
                float pv = __builtin_amdgcn_exp2f(s[t][r]);
                s[t][r] = pv;
                rs += pv;
            }
        rs += __shfl_xor(rs, 32, 64);
        l_run += rs;

        // ---- P -> A-frags in-register (cvt_pk + permlane32_swap)
        short8 pf[2][2];
        #pragma unroll
        for (int t = 0; t < 2; ++t)
            #pragma unroll
            for (int kc = 0; kc < 2; ++kc) {
                unsigned A0 = pk_bf16(s[t][8 * kc + 0], s[t][8 * kc + 1]);
                unsigned A1 = pk_bf16(s[t][8 * kc + 2], s[t][8 * kc + 3]);
                unsigned B0 = pk_bf16(s[t][8 * kc + 4], s[t][8 * kc + 5]);
                unsigned B1 = pk_bf16(s[t][8 * kc + 6], s[t][8 * kc + 7]);
                plane32_swap(A0, B0);
                plane32_swap(A1, B1);
                uint4 fw = make_uint4(A0, A1, B0, B1);
                pf[t][kc] = __builtin_bit_cast(short8, fw);
            }

        // ---- PV
        __builtin_amdgcn_s_setprio(1);
        #pragma unroll
        for (int dt = 0; dt < 2; ++dt) {
            const int row = dt * 32 + l31;
            const int rm  = l31 & 7;
            #pragma unroll
            for (int t = 0; t < 2; ++t)
                #pragma unroll
                for (int kc = 0; kc < 2; ++kc) {
                    short8 vf = *(const short8*)
                        &vb_[row * 64 + (((4 * t + 2 * kc + hi) ^ rm) * 8)];
                    acc[dt] = mfma32(pf[t][kc], vf, acc[dt]);
                }
        }
        __builtin_amdgcn_s_setprio(0);
    }

    // ---- merge kv-halves in two 16KB dt-rounds (exact fp32 sums).
    // mrg: float[4096] at bytes 0..16383; Lx: float[128] at bytes 16384..16895.
    float* mrg = (float*)&SLDS[0];
    float* Lx  = (float*)&SLDS[8192];
    float inv_r = 0.f;

    __syncthreads();                      // all compute reads done
    if (half == 1) {                      // round 0: publish dt=0 + l
        #pragma unroll
        for (int r = 0; r < 16; ++r) {
            const int qr = (r & 3) + 8 * (r >> 2) + 4 * hi;
            mrg[qt * 1024 + qr * 32 + l31] = acc[0][r];
        }
        if (lane < 32)
            Lx[qt * 32 + lane] = l_run;
    }
    __syncthreads();
    if (half == 0) {                      // absorb + store dt=0
        const float lo = Lx[qt * 32 + l31];
        inv_r = 1.f / (l_run + lo);
        #pragma unroll
        for (int r = 0; r < 16; ++r) {
            const int qr = (r & 3) + 8 * (r >> 2) + 4 * hi;
            float invr = __shfl(inv_r, qr, 64);
            float oh = mrg[qt * 1024 + qr * 32 + l31];
            O[(size_t)(b * SEQ + q0 + qr) * EMBED + h * HDIM + l31]
                = f2bf((acc[0][r] + oh) * invr);
        }
    }
    __syncthreads();
    if (half == 1) {                      // round 1: publish dt=1
        #pragma unroll
        for (int r = 0; r < 16; ++r) {
            const int qr = (r & 3) + 8 * (r >> 2) + 4 * hi;
            mrg[qt * 1024 + qr * 32 + l31] = acc[1][r];
        }
    }
    __syncthreads();
    if (half == 0) {                      // absorb + store dt=1
        #pragma unroll
        for (int r = 0; r < 16; ++r) {
            const int qr = (r & 3) + 8 * (r >> 2) + 4 * hi;
            float invr = __shfl(inv_r, qr, 64);
            float oh = mrg[qt * 1024 + qr * 32 + l31];
            O[(size_t)(b * SEQ + q0 + qr) * EMBED + h * HDIM + 32 + l31]
                = f2bf((acc[1][r] + oh) * invr);
        }
    }
}

// ---------------------------------------------------------------------------
extern "C" void kernel_launch(void* const* d_in, const int* in_sizes, int n_in,
                              void* d_out, int out_size, void* d_ws, size_t ws_size,
                              hipStream_t stream)
{
    const float* x  = (const float*)d_in[0];
    const float* Wq = (const float*)d_in[1];
    const float* bq = (const float*)d_in[2];
    const float* Wk = (const float*)d_in[3];
    const float* bk = (const float*)d_in[4];
    const float* Wv = (const float*)d_in[5];
    const float* bv = (const float*)d_in[6];
    const float* Wo = (const float*)d_in[7];
    const float* bo = (const float*)d_in[8];
    float* out = (float*)d_out;

    const size_t ME = (size_t)MTOT * EMBED;
    unsigned short* xh   = (unsigned short*)d_ws;     // 8 MB each
    unsigned short* Qb   = xh   + ME;
    unsigned short* Kb   = Qb   + ME;
    unsigned short* Vt   = Kb   + ME;                 // [b][h][d][s]
    unsigned short* attn = Vt   + ME;
    unsigned short* Wh   = attn + ME;                 // 4 x 2 MB packed

    dim3 blk(256);

    conv_all<<<dim3((2 * ME) / 2048), blk, 0, stream>>>(x, Wq, Wk, Wv, Wo, xh, Wh);

    gemm_qkv_pipe<<<dim3(12, MTOT / 256), dim3(512), 0, stream>>>(
        xh, Wh, Wh + (size_t)EMBED * EMBED, Wh + 2 * (size_t)EMBED * EMBED,
        bq, bk, bv, Qb, Kb, Vt);

    flash_attn_mfma9<<<dim3(SEQ / 128, HEADS, BATCH), dim3(512), 0, stream>>>(
        Qb, Kb, Vt, attn);

    gemm_o_bf16<<<dim3(EMBED / 128, MTOT / 128), blk, 0, stream>>>(
        attn, Wh + 3 * (size_t)EMBED * EMBED, bo, out);
}

// Round 19
// 114.297 us; speedup vs baseline: 1.0165x; 1.0165x over previous
//
#include <hip/hip_runtime.h>
#include <cstddef>

#define EMBED 1024
#define HEADS 16
#define HDIM  64
#define BATCH 2
#define SEQ   2048
#define MTOT  (BATCH*SEQ)

typedef __attribute__((ext_vector_type(8)))  short short8;   // 8 bf16 = 4 VGPRs
typedef __attribute__((ext_vector_type(4)))  float f32x4;    // 16x16 C/D frag
typedef __attribute__((ext_vector_type(16))) float f32x16;   // 32x32 C/D frag

typedef __attribute__((address_space(1))) const unsigned int* gas_u32p;
typedef __attribute__((address_space(3))) unsigned int* las_u32p;

// async global->LDS, 16B per lane; LDS dest = wave-uniform base + lane*16
static __device__ __forceinline__ void gload_lds16(const void* g, void* l) {
    __builtin_amdgcn_global_load_lds((gas_u32p)g, (las_u32p)l, 16, 0, 0);
}

// fp32 -> bf16 round-to-nearest-even
static __device__ __forceinline__ unsigned short f2bf(float x) {
    unsigned u = __builtin_bit_cast(unsigned, x);
    unsigned r = (u + 0x7FFFu + ((u >> 16) & 1u)) >> 16;
    return (unsigned short)r;
}

// pack two fp32 -> one u32 of 2 bf16 (hardware cvt)
static __device__ __forceinline__ unsigned pk_bf16(float lo, float hi) {
    unsigned r;
    asm("v_cvt_pk_bf16_f32 %0, %1, %2" : "=v"(r) : "v"(lo), "v"(hi));
    return r;
}

// swap: a' = {a.lo-lanes | b.lo-lanes}, b' = {a.hi-lanes | b.hi-lanes}
static __device__ __forceinline__ void plane32_swap(unsigned &a, unsigned &b) {
    auto r = __builtin_amdgcn_permlane32_swap((int)a, (int)b, false, false);
    a = (unsigned)r[0];
    b = (unsigned)r[1];
}

static __device__ __forceinline__ f32x16 mfma32(short8 a, short8 b, f32x16 c) {
    return __builtin_amdgcn_mfma_f32_32x32x16_bf16(a, b, c, 0, 0, 0);
}

// ---------------------------------------------------------------------------
// conv_all: x (4M elems) then Wq|Wk|Wv|Wo (4x1M elems) fp32 -> bf16
// ---------------------------------------------------------------------------
__global__ __launch_bounds__(256)
void conv_all(const float* __restrict__ x,
              const float* __restrict__ Wq, const float* __restrict__ Wk,
              const float* __restrict__ Wv, const float* __restrict__ Wo,
              unsigned short* __restrict__ xh, unsigned short* __restrict__ Wh)
{
    const size_t i = ((size_t)blockIdx.x * 256 + threadIdx.x) * 8;
    const size_t XTOT = (size_t)MTOT * EMBED;           // 4M
    const float* src;
    unsigned short* dst;
    size_t off;
    if (i < XTOT) {
        src = x; dst = xh; off = i;
    } else {
        size_t j = i - XTOT;
        int sel = (int)(j >> 20);
        off = j & ((1u << 20) - 1);
        src = sel == 0 ? Wq : sel == 1 ? Wk : sel == 2 ? Wv : Wo;
        dst = Wh + ((size_t)sel << 20);
    }
    float4 a = *(const float4*)(src + off);
    float4 b = *(const float4*)(src + off + 4);
    unsigned short o[8] __attribute__((aligned(16)));
    o[0] = f2bf(a.x); o[1] = f2bf(a.y); o[2] = f2bf(a.z); o[3] = f2bf(a.w);
    o[4] = f2bf(b.x); o[5] = f2bf(b.y); o[6] = f2bf(b.z); o[7] = f2bf(b.w);
    *(uint4*)(dst + off) = *(const uint4*)o;
}

// ---------------------------------------------------------------------------
// Fused QKV GEMM v3 (R17-proven): 256x256 tile, BK=32, 8 waves, 3-buffer
// LDS rotation with counted vmcnt(4) (T3+T4). Loads span ~2 tiles of
// compute; vmcnt(0) only at the j=30 drain. 2-bit source-XOR swizzle.
// ---------------------------------------------------------------------------
__global__ __launch_bounds__(512, 2)
void gemm_qkv_pipe(const unsigned short* __restrict__ A,
                   const unsigned short* __restrict__ Wqh,
                   const unsigned short* __restrict__ Wkh,
                   const unsigned short* __restrict__ Wvh,
                   const float* __restrict__ bq,
                   const float* __restrict__ bk,
                   const float* __restrict__ bv,
                   unsigned short* __restrict__ Qb,
                   unsigned short* __restrict__ Kb,
                   unsigned short* __restrict__ Vt)
{
    __shared__ short AL[3][256 * 32];   // 3 x 16KB
    __shared__ short BL[3][256 * 32];   // 3 x 16KB   (96KB total)

    const int tid  = threadIdx.x;
    const int lane = tid & 63;
    const int w    = tid >> 6;        // 0..7
    const int wm   = w >> 2;          // 0..1 : A-half (rows wm*128..+127)
    const int wn   = w & 3;           // 0..3 : B-quarter (cols wn*64..+63)
    const int c    = lane & 15;
    const int g    = lane >> 4;

    const int m0   = blockIdx.y * 256;
    const int wsel = blockIdx.x >> 2;
    const int n0   = (blockIdx.x & 3) * 256;

    const unsigned short* W = (wsel == 0) ? Wqh : (wsel == 1) ? Wkh : Wvh;
    const float* bias       = (wsel == 0) ? bq  : (wsel == 1) ? bk  : bv;

    const int r0 = tid >> 2;                       // 0..127
    const int sc = (tid & 3) ^ ((r0 >> 1) & 3);
    const unsigned short* aS0 = A + (size_t)(m0 + r0)       * EMBED + sc * 8;
    const unsigned short* aS1 = A + (size_t)(m0 + 128 + r0) * EMBED + sc * 8;
    const unsigned short* bS0 = W + (size_t)(n0 + r0)       * EMBED + sc * 8;
    const unsigned short* bS1 = W + (size_t)(n0 + 128 + r0) * EMBED + sc * 8;
    const int d0 = w * 512;
    const int d1 = 4096 + w * 512;

    #define STG_A(bj) do {                         \
        gload_lds16(aS0, &AL[bj][d0]);             \
        gload_lds16(aS1, &AL[bj][d1]);             \
        aS0 += 32; aS1 += 32; } while (0)
    #define STG_B(bj) do {                         \
        gload_lds16(bS0, &BL[bj][d0]);             \
        gload_lds16(bS1, &BL[bj][d1]);             \
        bS0 += 32; bS1 += 32; } while (0)

    f32x4 acc[8][4] = {};

    STG_A(0); STG_B(0);
    STG_A(1); STG_B(1);
    asm volatile("s_waitcnt vmcnt(4)" ::: "memory");
    __builtin_amdgcn_s_barrier();

    for (int j = 0; j < 32; ++j) {
        const int cb = j % 3;
        const int nb = (j + 2) % 3;
        const short* Ab = &AL[cb][0];
        const short* Bb = &BL[cb][0];

        short8 af[4], bf[4];

        #pragma unroll
        for (int ni = 0; ni < 4; ++ni) {
            const int row = wn * 64 + ni * 16 + c;
            const int cn  = g ^ ((row >> 1) & 3);
            bf[ni] = *(const short8*)&Bb[row * 32 + cn * 8];
        }
        #pragma unroll
        for (int mi = 0; mi < 4; ++mi) {
            const int row = wm * 128 + mi * 16 + c;
            const int cn  = g ^ ((row >> 1) & 3);
            af[mi] = *(const short8*)&Ab[row * 32 + cn * 8];
        }
        if (j < 30) STG_A(nb);
        __builtin_amdgcn_s_barrier();
        __builtin_amdgcn_s_setprio(1);
        #pragma unroll
        for (int mi = 0; mi < 4; ++mi)
            #pragma unroll
            for (int ni = 0; ni < 4; ++ni)
                acc[mi][ni] = __builtin_amdgcn_mfma_f32_16x16x32_bf16(
                    af[mi], bf[ni], acc[mi][ni], 0, 0, 0);
        __builtin_amdgcn_s_setprio(0);
        __builtin_amdgcn_s_barrier();

        #pragma unroll
        for (int mi = 0; mi < 4; ++mi) {
            const int row = wm * 128 + 64 + mi * 16 + c;
            const int cn  = g ^ ((row >> 1) & 3);
            af[mi] = *(const short8*)&Ab[row * 32 + cn * 8];
        }
        if (j < 30) STG_B(nb);
        __builtin_amdgcn_s_barrier();
        __builtin_amdgcn_s_setprio(1);
        #pragma unroll
        for (int mi = 0; mi < 4; ++mi)
            #pragma unroll
            for (int ni = 0; ni < 4; ++ni)
                acc[4 + mi][ni] = __builtin_amdgcn_mfma_f32_16x16x32_bf16(
                    af[mi], bf[ni], acc[4 + mi][ni], 0, 0, 0);
        __builtin_amdgcn_s_setprio(0);
        if (j < 30)       asm volatile("s_waitcnt vmcnt(4)" ::: "memory");
        else if (j == 30) asm volatile("s_waitcnt vmcnt(0)" ::: "memory");
        __builtin_amdgcn_s_barrier();
    }
    #undef STG_A
    #undef STG_B

    if (wsel == 2) {
        #pragma unroll
        for (int mi8 = 0; mi8 < 8; ++mi8) {
            const int m  = m0 + wm * 128 + (mi8 >> 2) * 64 + (mi8 & 3) * 16 + g * 4;
            const int bb = m >> 11;
            const int ss = m & (SEQ - 1);
            #pragma unroll
            for (int ni = 0; ni < 4; ++ni) {
                const int col = n0 + wn * 64 + ni * 16 + c;
                const int hh = col >> 6, dd = col & 63;
                const float bi_ = bias[col];
                ushort4 o;
                o.x = f2bf(acc[mi8][ni][0] + bi_);
                o.y = f2bf(acc[mi8][ni][1] + bi_);
                o.z = f2bf(acc[mi8][ni][2] + bi_);
                o.w = f2bf(acc[mi8][ni][3] + bi_);
                *(ushort4*)&Vt[((size_t)((bb * HEADS + hh) * HDIM) + dd) * SEQ + ss] = o;
            }
        }
    } else {
        unsigned short* Out = (wsel == 0) ? Qb : Kb;
        const float oscale  = (wsel == 0) ? 0.180336880f : 1.0f;  // 0.125*log2(e)
        #pragma unroll
        for (int mi8 = 0; mi8 < 8; ++mi8)
            #pragma unroll
            for (int r = 0; r < 4; ++r) {
                const int m = m0 + wm * 128 + (mi8 >> 2) * 64 + (mi8 & 3) * 16
                            + g * 4 + r;
                #pragma unroll
                for (int ni = 0; ni < 4; ++ni) {
                    const int col = n0 + wn * 64 + ni * 16 + c;
                    Out[(size_t)m * EMBED + col] =
                        f2bf((acc[mi8][ni][r] + bias[col]) * oscale);
                }
            }
    }
}

// ---------------------------------------------------------------------------
// Output GEMM: R13-proven mirror of R12 (BK=64 + source-XOR swizzle).
// ---------------------------------------------------------------------------
__global__ __launch_bounds__(256)
void gemm_o_bf16(const unsigned short* __restrict__ A,
                 const unsigned short* __restrict__ Woh,
                 const float* __restrict__ bo,
                 float* __restrict__ C)
{
    __shared__ short As[128 * 64];
    __shared__ short Bs[128 * 64];

    const int tid  = threadIdx.x;
    const int lane = tid & 63;
    const int w    = tid >> 6;
    const int c    = lane & 15;
    const int g    = lane >> 4;
    const int wr   = w >> 1;
    const int wc   = w & 1;

    const int m0 = blockIdx.y * 128;
    const int n0 = blockIdx.x * 128;

    f32x4 acc[4][4] = {};

    for (int k0 = 0; k0 < EMBED; k0 += 64) {
        __syncthreads();
        #pragma unroll
        for (int i = 0; i < 4; ++i) {
            const int slot = w * 256 + i * 64 + lane;
            const int row  = slot >> 3;
            const int chs  = (slot & 7) ^ (row & 7);
            gload_lds16(A   + (size_t)(m0 + row) * EMBED + k0 + chs * 8,
                        As + (size_t)(w * 256 + i * 64) * 8);
            gload_lds16(Woh + (size_t)(n0 + row) * EMBED + k0 + chs * 8,
                        Bs + (size_t)(w * 256 + i * 64) * 8);
        }
        __syncthreads();

        #pragma unroll
        for (int ks = 0; ks < 2; ++ks) {
            short8 af[4], bf[4];
            #pragma unroll
            for (int mi = 0; mi < 4; ++mi) {
                const int row = wr * 64 + mi * 16 + c;
                const int chn = (ks * 4 + g) ^ (row & 7);
                af[mi] = *(const short8*)&As[row * 64 + chn * 8];
            }
            #pragma unroll
            for (int ni = 0; ni < 4; ++ni) {
                const int row = wc * 64 + ni * 16 + c;
                const int chn = (ks * 4 + g) ^ (row & 7);
                bf[ni] = *(const short8*)&Bs[row * 64 + chn * 8];
            }
            #pragma unroll
            for (int mi = 0; mi < 4; ++mi)
                #pragma unroll
                for (int ni = 0; ni < 4; ++ni)
                    acc[mi][ni] = __builtin_amdgcn_mfma_f32_16x16x32_bf16(
                        af[mi], bf[ni], acc[mi][ni], 0, 0, 0);
        }
    }

    #pragma unroll
    for (int mi = 0; mi < 4; ++mi)
        #pragma unroll
        for (int r = 0; r < 4; ++r) {
            const int m = m0 + wr * 64 + mi * 16 + g * 4 + r;
            #pragma unroll
            for (int ni = 0; ni < 4; ++ni) {
                const int col = n0 + wc * 64 + ni * 16 + c;
                C[(size_t)m * EMBED + col] = acc[mi][ni][r] + bo[col];
            }
        }
}

// ---------------------------------------------------------------------------
// MFMA flash attention v5 — R17-proven, byte-identical (47.6us, 33% occ;
// grid = 2 blocks/CU exactly, so LDS diets don't raise occupancy — R18).
// ---------------------------------------------------------------------------
__global__ __launch_bounds__(512, 4)
void flash_attn_mfma5(const unsigned short* __restrict__ Qb,
                      const unsigned short* __restrict__ Kb,
                      const unsigned short* __restrict__ Vt,
                      unsigned short* __restrict__ O)
{
    __shared__ short KT[2][2][64 * 64];   // [half][buf][kv][d]  (swizzled chunks)
    __shared__ short VT[2][2][64 * 64];   // [half][buf][d][kv]

    const int tid  = threadIdx.x;
    const int lane = tid & 63;
    const int w    = tid >> 6;            // 0..7
    const int qt   = w & 3;               // q subtile
    const int half = w >> 2;              // kv half
    const int l31  = lane & 31;
    const int hi   = lane >> 5;
    const int q0   = blockIdx.x * 128 + qt * 32;
    const int h    = blockIdx.y;
    const int b    = blockIdx.z;

    // persistent Q B-frags: qf[kc] holds Q[q=l31][d = kc*16 + hi*8 + j]
    short8 qf[4];
    {
        const unsigned short* qrow =
            Qb + (size_t)(b * SEQ + q0 + l31) * EMBED + h * HDIM + hi * 8;
        #pragma unroll
        for (int kc = 0; kc < 4; ++kc)
            qf[kc] = *(const short8*)(qrow + kc * 16);
    }

    // staging: tile tb = w>>1 (0=K_lo,1=V_lo,2=K_hi,3=V_hi), ssub = w&1.
    const int tb     = w >> 1;
    const int sthalf = tb >> 1;
    const int stV    = tb & 1;
    const int ssub   = w & 1;
    const int strow  = ssub * 32 + (lane >> 3);
    const int ch     = (lane & 7) ^ (strow & 7);
    const unsigned short* kS =
        Kb + (size_t)(b * SEQ + sthalf * (SEQ / 2) + strow) * EMBED + h * HDIM + ch * 8;
    const unsigned short* vS =
        Vt + ((size_t)((b * HEADS + h) * HDIM) + strow) * SEQ + sthalf * (SEQ / 2) + ch * 8;

    f32x16 acc[2] = {};
    float l_run = 0.f;

    #define STAGE(kt2, bb)                                                    \
        do {                                                                  \
            if (stV == 0) {                                                   \
                const unsigned short* src = kS + (size_t)(kt2) * 64 * EMBED;  \
                short* kd = &KT[sthalf][bb][ssub * 2048];                     \
                _Pragma("unroll")                                             \
                for (int it = 0; it < 4; ++it)                                \
                    gload_lds16(src + (size_t)it * 8 * EMBED, kd + it * 512); \
            } else {                                                          \
                const unsigned short* src = vS + (kt2) * 64;                  \
                short* vd = &VT[sthalf][bb][ssub * 2048];                     \
                _Pragma("unroll")                                             \
                for (int it = 0; it < 4; ++it)                                \
                    gload_lds16(src + (size_t)it * 8 * SEQ, vd + it * 512);   \
            }                                                                 \
        } while (0)

    STAGE(0, 0);
    __syncthreads();

    for (int kt = 0; kt < SEQ / 2 / 64; ++kt) {
        const int bi = kt & 1;
        if (kt < SEQ / 2 / 64 - 1) STAGE(kt + 1, bi ^ 1);

        const short* kb_ = &KT[half][bi][0];
        const short* vb_ = &VT[half][bi][0];

        // ---- QK^T (C: col=l31=q, row=kv via qr formula)
        f32x16 s[2] = {};
        __builtin_amdgcn_s_setprio(1);
        #pragma unroll
        for (int t = 0; t < 2; ++t) {
            const int row = t * 32 + l31;
            const int rm  = l31 & 7;
            #pragma unroll
            for (int kc = 0; kc < 4; ++kc) {
                short8 ka = *(const short8*)&kb_[row * 64 + (((2 * kc + hi) ^ rm) * 8)];
                s[t] = mfma32(ka, qf[kc], s[t]);
            }
        }
        __builtin_amdgcn_s_setprio(0);

        // ---- P = exp2(s'), row-sum (fixed-base softmax: no max machinery)
        float rs = 0.f;
        #pragma unroll
        for (int t = 0; t < 2; ++t)
            #pragma unroll
            for (int r = 0; r < 16; ++r) {
                float pv = __builtin_amdgcn_exp2f(s[t][r]);
                s[t][r] = pv;
                rs += pv;
            }
        rs += __shfl_xor(rs, 32, 64);
        l_run += rs;

        // ---- P -> A-frags in-register (cvt_pk + permlane32_swap)
        short8 pf[2][2];
        #pragma unroll
        for (int t = 0; t < 2; ++t)
            #pragma unroll
            for (int kc = 0; kc < 2; ++kc) {
                unsigned A0 = pk_bf16(s[t][8 * kc + 0], s[t][8 * kc + 1]);
                unsigned A1 = pk_bf16(s[t][8 * kc + 2], s[t][8 * kc + 3]);
                unsigned B0 = pk_bf16(s[t][8 * kc + 4], s[t][8 * kc + 5]);
                unsigned B1 = pk_bf16(s[t][8 * kc + 6], s[t][8 * kc + 7]);
                plane32_swap(A0, B0);
                plane32_swap(A1, B1);
                uint4 fw = make_uint4(A0, A1, B0, B1);
                pf[t][kc] = __builtin_bit_cast(short8, fw);
            }

        // ---- PV
        __builtin_amdgcn_s_setprio(1);
        #pragma unroll
        for (int dt = 0; dt < 2; ++dt) {
            const int row = dt * 32 + l31;
            const int rm  = l31 & 7;
            #pragma unroll
            for (int t = 0; t < 2; ++t)
                #pragma unroll
                for (int kc = 0; kc < 2; ++kc) {
                    short8 vf = *(const short8*)
                        &vb_[row * 64 + (((4 * t + 2 * kc + hi) ^ rm) * 8)];
                    acc[dt] = mfma32(pf[t][kc], vf, acc[dt]);
                }
        }
        __builtin_amdgcn_s_setprio(0);

        __syncthreads();
    }
    #undef STAGE

    // ---- merge kv-halves: O = (O_lo + O_hi) / (l_lo + l_hi)  (exact fp32)
    float* mrgf = (float*)&KT[0][0][0];   // 4 pairs x 32q x 64d fp32 = 32KB
    float* mlbf = (float*)&VT[0][0][0];   // 4 pairs x 32q l-values
    if (half == 1) {
        #pragma unroll
        for (int dt = 0; dt < 2; ++dt)
            #pragma unroll
            for (int r = 0; r < 16; ++r) {
                const int qr = (r & 3) + 8 * (r >> 2) + 4 * hi;
                mrgf[qt * 2048 + qr * 64 + dt * 32 + l31] = acc[dt][r];
            }
        if (lane < 32)
            mlbf[qt * 32 + lane] = l_run;
    }
    __syncthreads();
    if (half == 0) {
        const float lo  = mlbf[qt * 32 + l31];
        const float inv = 1.f / (l_run + lo);
        #pragma unroll
        for (int r = 0; r < 16; ++r) {
            const int qr = (r & 3) + 8 * (r >> 2) + 4 * hi;
            float invr = __shfl(inv, qr, 64);
            #pragma unroll
            for (int dt = 0; dt < 2; ++dt) {
                float oh  = mrgf[qt * 2048 + qr * 64 + dt * 32 + l31];
                float val = (acc[dt][r] + oh) * invr;
                O[(size_t)(b * SEQ + q0 + qr) * EMBED + h * HDIM + dt * 32 + l31]
                    = f2bf(val);
            }
        }
    }
}

// ---------------------------------------------------------------------------
extern "C" void kernel_launch(void* const* d_in, const int* in_sizes, int n_in,
                              void* d_out, int out_size, void* d_ws, size_t ws_size,
                              hipStream_t stream)
{
    const float* x  = (const float*)d_in[0];
    const float* Wq = (const float*)d_in[1];
    const float* bq = (const float*)d_in[2];
    const float* Wk = (const float*)d_in[3];
    const float* bk = (const float*)d_in[4];
    const float* Wv = (const float*)d_in[5];
    const float* bv = (const float*)d_in[6];
    const float* Wo = (const float*)d_in[7];
    const float* bo = (const float*)d_in[8];
    float* out = (float*)d_out;

    const size_t ME = (size_t)MTOT * EMBED;
    unsigned short* xh   = (unsigned short*)d_ws;     // 8 MB each
    unsigned short* Qb   = xh   + ME;
    unsigned short* Kb   = Qb   + ME;
    unsigned short* Vt   = Kb   + ME;                 // [b][h][d][s]
    unsigned short* attn = Vt   + ME;
    unsigned short* Wh   = attn + ME;                 // 4 x 2 MB packed

    dim3 blk(256);

    conv_all<<<dim3((2 * ME) / 2048), blk, 0, stream>>>(x, Wq, Wk, Wv, Wo, xh, Wh);

    gemm_qkv_pipe<<<dim3(12, MTOT / 256), dim3(512), 0, stream>>>(
        xh, Wh, Wh + (size_t)EMBED * EMBED, Wh + 2 * (size_t)EMBED * EMBED,
        bq, bk, bv, Qb, Kb, Vt);

    flash_attn_mfma5<<<dim3(SEQ / 128, HEADS, BATCH), dim3(512), 0, stream>>>(
        Qb, Kb, Vt, attn);

    gemm_o_bf16<<<dim3(EMBED / 128, MTOT / 128), blk, 0, stream>>>(
        attn, Wh + 3 * (size_t)EMBED * EMBED, bo, out);
}